// Round 1
// baseline (973.218 us; speedup 1.0000x reference)
//
#include <hip/hip_runtime.h>
#include <stdint.h>

// KronQRInjectedLinear: out = ((input @ rot) @ Q) @ R_eff, all 4096x4096 GEMMs.
//   rot  = kron(Q1,Q2);  orth = kron(R1,R2)
//   R_eff = R + orth diag(lam) orth^T   (the delta term is symmetric)
// All GEMMs computed as C = A @ Bt^T with bf16 A,Bt (k-contiguous), fp32 accum.
// GEMM: 128x128 tile, BK=32, 4 waves x (4x4 of 16x16x32 MFMA), global_load_lds.
//
// ws layout (bytes):
//   [  0M, 32M) orth  bf16      -> reused as X1 after GEMM1
//   [ 32M, 64M) orthl bf16      -> reused as X2
//   [ 64M, 96M) rotT  bf16   (rotation^T)
//   [ 96M,128M) Qt    bf16   (Q^T)
//   [128M,160M) inbf  bf16   (input cast)
//   [160M,192M) rteff bf16   (R_eff^T = R^T + D)
// d_out doubles as scratch: Q1t f32 (16M, consumed before GEMM1), then D f32.

typedef unsigned short u16;
typedef short bf16x8 __attribute__((ext_vector_type(8)));
typedef float f32x4 __attribute__((ext_vector_type(4)));

__device__ __forceinline__ u16 f2bf(float f) {
  union { float f; uint32_t u; } v; v.f = f;
  return (u16)((v.u + 0x7FFFu + ((v.u >> 16) & 1u)) >> 16);
}

__device__ __forceinline__ void store_out(float* p, float v) { *p = v; }
__device__ __forceinline__ void store_out(u16* p, float v) { *p = f2bf(v); }

__device__ __forceinline__ void gload_lds16(const u16* g, u16* l) {
  __builtin_amdgcn_global_load_lds(
      (__attribute__((address_space(1))) void*)(uintptr_t)g,
      (__attribute__((address_space(3))) void*)l, 16, 0, 0);
}

// ---------------- GEMM: C[M,N] = A[M,K] @ Bt[N,K]^T ----------------
template <typename OutT>
__global__ __launch_bounds__(256) void gemm_bt(
    const u16* __restrict__ A, const u16* __restrict__ Bt, OutT* __restrict__ C,
    int M, int N, int K) {
  __shared__ __align__(16) u16 la[128 * 32];
  __shared__ __align__(16) u16 lb[128 * 32];
  const int tid  = (int)threadIdx.x;
  const int lane = tid & 63;
  const int w    = tid >> 6;         // wave 0..3
  const int wr   = w >> 1, wc = w & 1;
  const int brow = (int)blockIdx.y * 128;
  const int bcol = (int)blockIdx.x * 128;

  // staging: wave w fills LDS chunks c0,c1 (1024B each, lane*16B within chunk)
  const int l4 = lane >> 2;          // 0..15 : row within 16-row chunk
  const int lk = (lane & 3) << 3;    // 0,8,16,24 : k-offset (elems)
  const int c0 = w * 2, c1 = c0 + 1;
  const u16* a0 = A  + (size_t)(brow + c0 * 16 + l4) * K + lk;
  const u16* a1 = A  + (size_t)(brow + c1 * 16 + l4) * K + lk;
  const u16* b0 = Bt + (size_t)(bcol + c0 * 16 + l4) * K + lk;
  const u16* b1 = Bt + (size_t)(bcol + c1 * 16 + l4) * K + lk;
  u16* la0 = &la[c0 * 512]; u16* la1 = &la[c1 * 512];
  u16* lb0 = &lb[c0 * 512]; u16* lb1 = &lb[c1 * 512];

  // fragment read offsets (A: row = lane&15, k = (lane>>4)*8 + j)
  const int lr = lane & 15;
  const int lg = lane >> 4;
  const int aro = (wr * 64 + lr) * 32 + lg * 8;
  const int bro = (wc * 64 + lr) * 32 + lg * 8;

  f32x4 acc[4][4] = {};

  for (int k0 = 0; k0 < K; k0 += 32) {
    gload_lds16(a0 + k0, la0);
    gload_lds16(a1 + k0, la1);
    gload_lds16(b0 + k0, lb0);
    gload_lds16(b1 + k0, lb1);
    __syncthreads();
    bf16x8 af[4], bfr[4];
#pragma unroll
    for (int m = 0; m < 4; ++m) af[m]  = *(const bf16x8*)&la[aro + m * 512];
#pragma unroll
    for (int n = 0; n < 4; ++n) bfr[n] = *(const bf16x8*)&lb[bro + n * 512];
#pragma unroll
    for (int m = 0; m < 4; ++m)
#pragma unroll
      for (int n = 0; n < 4; ++n)
        acc[m][n] = __builtin_amdgcn_mfma_f32_16x16x32_bf16(af[m], bfr[n], acc[m][n], 0, 0, 0);
    __syncthreads();
  }

  // C/D layout: col = lane&15, row = (lane>>4)*4 + j
#pragma unroll
  for (int m = 0; m < 4; ++m) {
    const int r0 = brow + wr * 64 + m * 16 + lg * 4;
#pragma unroll
    for (int n = 0; n < 4; ++n) {
      const int cc = bcol + wc * 64 + n * 16 + lr;
#pragma unroll
      for (int j = 0; j < 4; ++j)
        store_out(&C[(size_t)(r0 + j) * N + cc], acc[m][n][j]);
    }
  }
}

// ---------------- tiled transpose: out[c][r] = in[r][c] ----------------
template <typename OutT>
__global__ void trans_kernel(const float* __restrict__ in, OutT* __restrict__ out, int n) {
  __shared__ float t[32][33];
  const int bx = (int)blockIdx.x * 32, by = (int)blockIdx.y * 32;
  const int x = (int)threadIdx.x, y0 = (int)threadIdx.y;
#pragma unroll
  for (int dy = 0; dy < 32; dy += 8)
    t[y0 + dy][x] = in[(size_t)(bx + y0 + dy) * n + by + x];
  __syncthreads();
#pragma unroll
  for (int dy = 0; dy < 32; dy += 8)
    store_out(&out[(size_t)(by + y0 + dy) * n + bx + x], t[x][y0 + dy]);
}

// rteff[i][j] = bf16(R[j][i] + D[i][j])  (D symmetric -> this is R_eff^T)
__global__ void transadd_kernel(const float* __restrict__ R, const float* __restrict__ D,
                                u16* __restrict__ out) {
  __shared__ float t[32][33];
  const int bx = (int)blockIdx.x * 32, by = (int)blockIdx.y * 32;
  const int x = (int)threadIdx.x, y0 = (int)threadIdx.y;
#pragma unroll
  for (int dy = 0; dy < 32; dy += 8)
    t[y0 + dy][x] = R[(size_t)(bx + y0 + dy) * 4096 + by + x];
  __syncthreads();
#pragma unroll
  for (int dy = 0; dy < 32; dy += 8) {
    const size_t o = (size_t)(by + y0 + dy) * 4096 + bx + x;
    out[o] = f2bf(t[x][y0 + dy] + D[o]);
  }
}

// materialize rotT = kron(Q1,Q2)^T, orth = kron(R1,R2), orthl = orth * lam[col]
__global__ void prep_kron(const float* __restrict__ Q1t, const float* __restrict__ Q2,
                          const float* __restrict__ R1,  const float* __restrict__ R2,
                          const float* __restrict__ lam,
                          u16* __restrict__ rotT, u16* __restrict__ orth,
                          u16* __restrict__ orthl) {
  const size_t idx = (size_t)blockIdx.x * blockDim.x + threadIdx.x;
  const int i = (int)(idx >> 12);
  const int j = (int)(idx & 4095);
  // rotT[i][j] = rot[j][i] = Q1[j/2][i/2]*Q2[j%2][i%2] = Q1t[i/2][j/2]*Q2[j%2][i%2]
  const float rv = Q1t[((size_t)(i >> 1) << 11) + (j >> 1)] * Q2[((j & 1) << 1) + (i & 1)];
  rotT[idx] = f2bf(rv);
  const float ov = R1[((size_t)(i >> 1) << 11) + (j >> 1)] * R2[((i & 1) << 1) + (j & 1)];
  orth[idx]  = f2bf(ov);
  orthl[idx] = f2bf(ov * lam[j]);
}

__global__ void cast_kernel(const float* __restrict__ in, u16* __restrict__ out, int n4) {
  const int i = (int)blockIdx.x * (int)blockDim.x + (int)threadIdx.x;
  if (i < n4) {
    const float4 v = ((const float4*)in)[i];
    ushort4 o;
    o.x = f2bf(v.x); o.y = f2bf(v.y); o.z = f2bf(v.z); o.w = f2bf(v.w);
    ((ushort4*)out)[i] = o;
  }
}

extern "C" void kernel_launch(void* const* d_in, const int* in_sizes, int n_in,
                              void* d_out, int out_size, void* d_ws, size_t ws_size,
                              hipStream_t stream) {
  const float* input = (const float*)d_in[0];
  const float* Q     = (const float*)d_in[1];
  const float* R     = (const float*)d_in[2];
  const float* Q1    = (const float*)d_in[3];
  const float* Q2    = (const float*)d_in[4];
  const float* R1    = (const float*)d_in[5];
  const float* R2    = (const float*)d_in[6];
  const float* lam   = (const float*)d_in[7];
  float* out = (float*)d_out;

  const size_t MB = 1024ull * 1024ull;
  char* ws = (char*)d_ws;
  u16* orth  = (u16*)(ws + 0 * MB);
  u16* orthl = (u16*)(ws + 32 * MB);
  u16* rotT  = (u16*)(ws + 64 * MB);
  u16* Qt    = (u16*)(ws + 96 * MB);
  u16* inbf  = (u16*)(ws + 128 * MB);
  u16* rteff = (u16*)(ws + 160 * MB);   // needs ws_size >= 192 MB
  u16* X1 = orth;    // orth/orthl dead after GEMM1
  u16* X2 = orthl;
  float* Q1t = (float*)d_out;           // consumed before GEMM1 writes D
  float* D   = (float*)d_out;

  const dim3 tb(32, 8);
  // 1) Q1t = Q1^T (2048x2048 f32)
  trans_kernel<float><<<dim3(64, 64), tb, 0, stream>>>(Q1, Q1t, 2048);
  // 2) materialize kron factors (bf16)
  prep_kron<<<65536, 256, 0, stream>>>(Q1t, Q2, R1, R2, lam, rotT, orth, orthl);
  // 3) Qt = Q^T (bf16)
  trans_kernel<u16><<<dim3(128, 128), tb, 0, stream>>>(Q, Qt, 4096);
  // 4) input -> bf16
  cast_kernel<<<16384, 256, 0, stream>>>(input, inbf, 4194304);
  // 5) D = (orth*lam) @ orth^T   (fp32, into d_out)
  gemm_bt<float><<<dim3(32, 32), 256, 0, stream>>>(orthl, orth, D, 4096, 4096, 4096);
  // 6) rteff = R^T + D  (bf16)
  transadd_kernel<<<dim3(128, 128), tb, 0, stream>>>(R, D, rteff);
  // 7) X1 = input @ rotation      (= inbf @ rotT^T)
  gemm_bt<u16><<<dim3(32, 32), 256, 0, stream>>>(inbf, rotT, X1, 4096, 4096, 4096);
  // 8) X2 = X1 @ Q                (= X1 @ Qt^T)
  gemm_bt<u16><<<dim3(32, 32), 256, 0, stream>>>(X1, Qt, X2, 4096, 4096, 4096);
  // 9) out = X2 @ R_eff           (= X2 @ rteff^T, fp32)
  gemm_bt<float><<<dim3(32, 32), 256, 0, stream>>>(X2, rteff, out, 4096, 4096, 4096);
}

// Round 2
// 622.015 us; speedup vs baseline: 1.5646x; 1.5646x over previous
//
#include <hip/hip_runtime.h>
#include <stdint.h>

// KronQRInjectedLinear: out = ((input @ rot) @ Q) @ R_eff, 4 x 4096^3 GEMMs.
// GEMM: 256x256 tile, 8 waves, K chunked by 32 into 4 rotating LDS slots,
// 8-phase-style schedule: counted vmcnt(8) (3 chunks prefetch depth),
// XOR-swizzled LDS reads with pre-swizzled global_load_lds sources,
// setprio around MFMA clusters, XCD-aware block swizzle.

typedef unsigned short u16;
typedef short bf16x8 __attribute__((ext_vector_type(8)));
typedef float f32x4 __attribute__((ext_vector_type(4)));

__device__ __forceinline__ u16 f2bf(float f) {
  union { float f; uint32_t u; } v; v.f = f;
  return (u16)((v.u + 0x7FFFu + ((v.u >> 16) & 1u)) >> 16);
}

__device__ __forceinline__ void store_out(float* p, float v) { *p = v; }
__device__ __forceinline__ void store_out(u16* p, float v) { *p = f2bf(v); }

__device__ __forceinline__ void gload_lds16(const u16* g, u16* l) {
  __builtin_amdgcn_global_load_lds(
      (__attribute__((address_space(1))) void*)(uintptr_t)g,
      (__attribute__((address_space(3))) void*)l, 16, 0, 0);
}

// ---------------- GEMM: C[M,N] = A[M,K] @ Bt[N,K]^T ----------------
// 256x256 tile, 512 threads. LDS: A,B each 4 slots x (256 rows x 32 k) bf16.
// Chunk layout: row pair (2r,2r+1) packed into one 128B LDS row; 16B k-slot
// index swizzled by XOR with (r&7). Readers and stagers share the mapping:
//   elem (r,k): r'=r>>1, ks' = (k>>3)+4*(r&1), ks'' = ks' ^ (r'&7)
//   byte = r'*128 + ks''*16 + (k&7)*2
template <typename OutT>
__global__ __launch_bounds__(512, 2) void gemm256(
    const u16* __restrict__ A, const u16* __restrict__ Bt, OutT* __restrict__ C,
    int M, int N, int K) {
  extern __shared__ __align__(16) u16 smem[];
  u16* ldsA = smem;           // 4 slots x 8192 elems (64 KB)
  u16* ldsB = smem + 32768;   // 4 slots x 8192 elems (64 KB)

  const int tid  = (int)threadIdx.x;
  const int lane = tid & 63;
  const int wid  = tid >> 6;       // 0..7
  const int wr   = wid >> 2;       // 0..1 : M half
  const int wc   = wid & 3;        // 0..3 : N quarter

  // XCD-aware bijective block swizzle (nwg = 256, divisible by 8)
  const int tilesX = N >> 8;
  const int nwg = tilesX * (M >> 8);
  const int bid = (int)blockIdx.y * (int)gridDim.x + (int)blockIdx.x;
  const int swz = (bid & 7) * (nwg >> 3) + (bid >> 3);
  const int brow = (swz / tilesX) << 8;
  const int bcol = (swz % tilesX) << 8;

  // fragment-read lane constants (swizzled slot is lane-constant across frags)
  const int lr = lane & 15, lg = lane >> 4, h = lr >> 1;
  const int sf = (lg + ((lr & 1) << 2)) ^ h;         // swizzled 16B slot
  const int aoff = (wr * 64 + h) * 64 + sf * 8;      // elems; + m*512 per frag
  const int boff = (wc * 32 + h) * 64 + sf * 8;      // elems; + n*512 per frag

  // staging constants: lane l of issue j writes LDS linearly at (j*8192+tid*16)B;
  // global source is inverse-swizzled so swizzled reads see logical data.
  const int kp   = (tid & 7) ^ ((tid >> 3) & 7);     // ks'
  const int srow = 2 * (tid >> 3) + (kp >> 2);       // 0..127
  const int scol = (kp & 3) << 3;                    // 0,8,16,24
  const size_t gA0 = (size_t)(brow + srow) * K + scol;
  const size_t gA1 = (size_t)(brow + 128 + srow) * K + scol;
  const size_t gB0 = (size_t)(bcol + srow) * K + scol;
  const size_t gB1 = (size_t)(bcol + 128 + srow) * K + scol;
  const int sOff0 = wid * 512;                       // wave-uniform LDS elems
  const int sOff1 = 4096 + wid * 512;

  const int NC = K >> 5;                             // 32-wide K chunks

  f32x4 acc[8][4] = {};

#define STAGE_A(cc) do { const int _s = ((cc) & 3) * 8192; const size_t _k = (size_t)(cc) * 32; \
    gload_lds16(A + gA0 + _k, ldsA + _s + sOff0);                                               \
    gload_lds16(A + gA1 + _k, ldsA + _s + sOff1); } while (0)
#define STAGE_B(cc) do { const int _s = ((cc) & 3) * 8192; const size_t _k = (size_t)(cc) * 32; \
    gload_lds16(Bt + gB0 + _k, ldsB + _s + sOff0);                                              \
    gload_lds16(Bt + gB1 + _k, ldsB + _s + sOff1); } while (0)

  // Prologue: chunks 0..2 in flight; wait chunk 0 (8 loads may stay outstanding).
  STAGE_A(0); STAGE_B(0); STAGE_A(1); STAGE_B(1); STAGE_A(2); STAGE_B(2);
  asm volatile("s_waitcnt vmcnt(8)" ::: "memory");
  __builtin_amdgcn_sched_barrier(0);
  __builtin_amdgcn_s_barrier();

#define CHUNK(c, DOSTAGE, TAILWAIT) do {                                        \
    const int _sl = ((c) & 3) * 8192;                                           \
    const u16* _pa = ldsA + _sl + aoff;                                         \
    const u16* _pb = ldsB + _sl + boff;                                         \
    bf16x8 af[8], bb[2];                                                        \
    _Pragma("unroll")                                                           \
    for (int m = 0; m < 8; ++m) af[m] = *(const bf16x8*)(_pa + m * 512);        \
    bb[0] = *(const bf16x8*)(_pb);                                              \
    bb[1] = *(const bf16x8*)(_pb + 512);                                        \
    if (DOSTAGE) STAGE_A((c) + 3);                                              \
    __builtin_amdgcn_s_barrier();                                               \
    asm volatile("s_waitcnt lgkmcnt(0)" ::: "memory");                          \
    __builtin_amdgcn_sched_barrier(0);                                          \
    __builtin_amdgcn_s_setprio(1);                                              \
    _Pragma("unroll")                                                           \
    for (int m = 0; m < 8; ++m) {                                               \
      acc[m][0] = __builtin_amdgcn_mfma_f32_16x16x32_bf16(af[m], bb[0], acc[m][0], 0, 0, 0); \
      acc[m][1] = __builtin_amdgcn_mfma_f32_16x16x32_bf16(af[m], bb[1], acc[m][1], 0, 0, 0); \
    }                                                                           \
    __builtin_amdgcn_s_setprio(0);                                              \
    __builtin_amdgcn_s_barrier();                                               \
    bb[0] = *(const bf16x8*)(_pb + 1024);                                       \
    bb[1] = *(const bf16x8*)(_pb + 1536);                                       \
    if (DOSTAGE) STAGE_B((c) + 3);                                              \
    __builtin_amdgcn_s_barrier();                                               \
    asm volatile("s_waitcnt lgkmcnt(0)" ::: "memory");                          \
    __builtin_amdgcn_sched_barrier(0);                                          \
    __builtin_amdgcn_s_setprio(1);                                              \
    _Pragma("unroll")                                                           \
    for (int m = 0; m < 8; ++m) {                                               \
      acc[m][2] = __builtin_amdgcn_mfma_f32_16x16x32_bf16(af[m], bb[0], acc[m][2], 0, 0, 0); \
      acc[m][3] = __builtin_amdgcn_mfma_f32_16x16x32_bf16(af[m], bb[1], acc[m][3], 0, 0, 0); \
    }                                                                           \
    __builtin_amdgcn_s_setprio(0);                                              \
    asm volatile("s_waitcnt " TAILWAIT ::: "memory");                           \
    __builtin_amdgcn_sched_barrier(0);                                          \
    __builtin_amdgcn_s_barrier();                                               \
  } while (0)

  // Steady state: stage chunk c+3, keep 4 pieces (8 loads) in flight.
  for (int c = 0; c + 3 < NC; ++c) CHUNK(c, 1, "vmcnt(8)");
  // Epilogue: drain 8 -> 4 -> 0.
  CHUNK(NC - 3, 0, "vmcnt(4)");
  CHUNK(NC - 2, 0, "vmcnt(0)");
  CHUNK(NC - 1, 0, "vmcnt(0)");

#undef CHUNK
#undef STAGE_A
#undef STAGE_B

  // C/D layout per 16x16 frag: col = lane&15, row = (lane>>4)*4 + j
#pragma unroll
  for (int m = 0; m < 8; ++m) {
    const int r0 = brow + wr * 128 + m * 16 + lg * 4;
#pragma unroll
    for (int n = 0; n < 4; ++n) {
      const int cc = bcol + wc * 64 + n * 16 + lr;
#pragma unroll
      for (int j = 0; j < 4; ++j)
        store_out(&C[(size_t)(r0 + j) * N + cc], acc[m][n][j]);
    }
  }
}

// ---------------- tiled transpose: out[c][r] = in[r][c] ----------------
template <typename OutT>
__global__ void trans_kernel(const float* __restrict__ in, OutT* __restrict__ out, int n) {
  __shared__ float t[32][33];
  const int bx = (int)blockIdx.x * 32, by = (int)blockIdx.y * 32;
  const int x = (int)threadIdx.x, y0 = (int)threadIdx.y;
#pragma unroll
  for (int dy = 0; dy < 32; dy += 8)
    t[y0 + dy][x] = in[(size_t)(bx + y0 + dy) * n + by + x];
  __syncthreads();
#pragma unroll
  for (int dy = 0; dy < 32; dy += 8)
    store_out(&out[(size_t)(by + y0 + dy) * n + bx + x], t[x][y0 + dy]);
}

// rteff[i][j] = bf16(R[j][i] + D[i][j])  (D symmetric -> this is R_eff^T)
__global__ void transadd_kernel(const float* __restrict__ R, const float* __restrict__ D,
                                u16* __restrict__ out) {
  __shared__ float t[32][33];
  const int bx = (int)blockIdx.x * 32, by = (int)blockIdx.y * 32;
  const int x = (int)threadIdx.x, y0 = (int)threadIdx.y;
#pragma unroll
  for (int dy = 0; dy < 32; dy += 8)
    t[y0 + dy][x] = R[(size_t)(bx + y0 + dy) * 4096 + by + x];
  __syncthreads();
#pragma unroll
  for (int dy = 0; dy < 32; dy += 8) {
    const size_t o = (size_t)(by + y0 + dy) * 4096 + bx + x;
    out[o] = f2bf(t[x][y0 + dy] + D[o]);
  }
}

// materialize rotT = kron(Q1,Q2)^T, orth = kron(R1,R2), orthl = orth * lam[col]
__global__ void prep_kron(const float* __restrict__ Q1t, const float* __restrict__ Q2,
                          const float* __restrict__ R1,  const float* __restrict__ R2,
                          const float* __restrict__ lam,
                          u16* __restrict__ rotT, u16* __restrict__ orth,
                          u16* __restrict__ orthl) {
  const size_t idx = (size_t)blockIdx.x * blockDim.x + threadIdx.x;
  const int i = (int)(idx >> 12);
  const int j = (int)(idx & 4095);
  const float rv = Q1t[((size_t)(i >> 1) << 11) + (j >> 1)] * Q2[((j & 1) << 1) + (i & 1)];
  rotT[idx] = f2bf(rv);
  const float ov = R1[((size_t)(i >> 1) << 11) + (j >> 1)] * R2[((i & 1) << 1) + (j & 1)];
  orth[idx]  = f2bf(ov);
  orthl[idx] = f2bf(ov * lam[j]);
}

__global__ void cast_kernel(const float* __restrict__ in, u16* __restrict__ out, int n4) {
  const int i = (int)blockIdx.x * (int)blockDim.x + (int)threadIdx.x;
  if (i < n4) {
    const float4 v = ((const float4*)in)[i];
    ushort4 o;
    o.x = f2bf(v.x); o.y = f2bf(v.y); o.z = f2bf(v.z); o.w = f2bf(v.w);
    ((ushort4*)out)[i] = o;
  }
}

extern "C" void kernel_launch(void* const* d_in, const int* in_sizes, int n_in,
                              void* d_out, int out_size, void* d_ws, size_t ws_size,
                              hipStream_t stream) {
  const float* input = (const float*)d_in[0];
  const float* Q     = (const float*)d_in[1];
  const float* R     = (const float*)d_in[2];
  const float* Q1    = (const float*)d_in[3];
  const float* Q2    = (const float*)d_in[4];
  const float* R1    = (const float*)d_in[5];
  const float* R2    = (const float*)d_in[6];
  const float* lam   = (const float*)d_in[7];
  float* out = (float*)d_out;

  const size_t MB = 1024ull * 1024ull;
  char* ws = (char*)d_ws;
  u16* orth  = (u16*)(ws + 0 * MB);
  u16* orthl = (u16*)(ws + 32 * MB);
  u16* rotT  = (u16*)(ws + 64 * MB);
  u16* Qt    = (u16*)(ws + 96 * MB);
  u16* inbf  = (u16*)(ws + 128 * MB);
  u16* rteff = (u16*)(ws + 160 * MB);   // needs ws_size >= 192 MB
  u16* X1 = orth;    // orth/orthl dead after GEMM1
  u16* X2 = orthl;
  float* Q1t = (float*)d_out;           // consumed before GEMM1 writes D
  float* D   = (float*)d_out;

  // opt-in to 128 KiB dynamic LDS for both gemm instantiations
  {
    void (*pf)(const u16*, const u16*, float*, int, int, int) = gemm256<float>;
    void (*pb)(const u16*, const u16*, u16*, int, int, int)   = gemm256<u16>;
    (void)hipFuncSetAttribute((const void*)pf, hipFuncAttributeMaxDynamicSharedMemorySize, 131072);
    (void)hipFuncSetAttribute((const void*)pb, hipFuncAttributeMaxDynamicSharedMemorySize, 131072);
  }

  const dim3 tb(32, 8);
  // 1) Q1t = Q1^T (2048x2048 f32)
  trans_kernel<float><<<dim3(64, 64), tb, 0, stream>>>(Q1, Q1t, 2048);
  // 2) materialize kron factors (bf16)
  prep_kron<<<65536, 256, 0, stream>>>(Q1t, Q2, R1, R2, lam, rotT, orth, orthl);
  // 3) Qt = Q^T (bf16)
  trans_kernel<u16><<<dim3(128, 128), tb, 0, stream>>>(Q, Qt, 4096);
  // 4) input -> bf16
  cast_kernel<<<16384, 256, 0, stream>>>(input, inbf, 4194304);
  // 5) D = (orth*lam) @ orth^T   (fp32, into d_out)
  gemm256<float><<<dim3(16, 16), 512, 131072, stream>>>(orthl, orth, D, 4096, 4096, 4096);
  // 6) rteff = R^T + D  (bf16)
  transadd_kernel<<<dim3(128, 128), tb, 0, stream>>>(R, D, rteff);
  // 7) X1 = input @ rotation      (= inbf @ rotT^T)
  gemm256<u16><<<dim3(16, 16), 512, 131072, stream>>>(inbf, rotT, X1, 4096, 4096, 4096);
  // 8) X2 = X1 @ Q                (= X1 @ Qt^T)
  gemm256<u16><<<dim3(16, 16), 512, 131072, stream>>>(X1, Qt, X2, 4096, 4096, 4096);
  // 9) out = X2 @ R_eff           (= X2 @ rteff^T, fp32)
  gemm256<float><<<dim3(16, 16), 512, 131072, stream>>>(X2, rteff, out, 4096, 4096, 4096);
}

// Round 4
// 493.636 us; speedup vs baseline: 1.9715x; 1.2601x over previous
//
#include <hip/hip_runtime.h>
#include <stdint.h>

// KronQRInjectedLinear: out = ((input @ rot) @ Q) @ R_eff.
// Kron structure exploited:
//   rot GEMM:  X1 = in @ kron(Q1,Q2) = [T_j2 = in·Q2-contract] @ Q1  (2x 4096x2048x2048, batched)
//   D term:    D = kron(R1,R2) diag(lam) kron(R1,R2)^T -> Dsub[s] = (R1 .* g_s) @ R1^T (4x 2048^3, batched)
//   X1 column interleave folded into permuted Q^T (Qtp).
// GEMM core: 256x256 tile, 8 waves, BK=32 chunks in 4 rotating swizzled LDS slots,
// balanced 2-phase schedule (8/4 ds_reads), counted vmcnt, setprio, XCD swizzle.
//
// ws layout (MB): R1bf 0-8 | Asc 8-40 (4 planes, later reused as X2) | Q1tb 40-48 |
//                 T 48-80 (2 planes) | Qtp 80-112 | rteff 112-144 | X1p 144-176
// d_out doubles as Dsub (4 x 2048^2 f32 = 64 MB), consumed by transadd before final GEMM.

typedef unsigned short u16;
typedef short bf16x8 __attribute__((ext_vector_type(8)));
typedef float f32x4 __attribute__((ext_vector_type(4)));

__device__ __forceinline__ u16 f2bf(float f) {
  union { float f; uint32_t u; } v; v.f = f;
  return (u16)((v.u + 0x7FFFu + ((v.u >> 16) & 1u)) >> 16);
}

__device__ __forceinline__ void store_out(float* p, float v) { *p = v; }
__device__ __forceinline__ void store_out(u16* p, float v) { *p = f2bf(v); }

__device__ __forceinline__ void gload_lds16(const u16* g, u16* l) {
  __builtin_amdgcn_global_load_lds(
      (__attribute__((address_space(1))) void*)(uintptr_t)g,
      (__attribute__((address_space(3))) void*)l, 16, 0, 0);
}

// ---------------- GEMM: C[M,N] = A[M,K] @ Bt[N,K]^T (batched on z) ----------------
// LDS chunk layout: elem (r,k) r<256,k<32 -> (r>>1)*64 + (((k>>3)+4*(r&1))^((r>>1)&7))*8 + (k&7)
template <typename OutT>
__global__ __launch_bounds__(512, 2) void gemm256(
    const u16* __restrict__ A, const u16* __restrict__ Bt, OutT* __restrict__ C,
    int M, int N, int K, int ldC, long long sA, long long sC) {
  extern __shared__ __align__(16) u16 smem[];
  u16* ldsA = smem;           // 4 slots x 8192 elems
  u16* ldsB = smem + 32768;

  const int tid  = (int)threadIdx.x;
  const int lane = tid & 63;
  const int wid  = tid >> 6;
  const int wr   = wid >> 2;       // 0..1 : M half
  const int wc   = wid & 3;        // 0..3 : N quarter

  // XCD-aware bijective swizzle over the full (x,y,z) grid; nwg % 8 == 0 everywhere.
  const int tilesX = (int)gridDim.x;
  const int tilesXY = tilesX * (int)gridDim.y;
  const int nwg = tilesXY * (int)gridDim.z;
  const int bid = ((int)blockIdx.z * (int)gridDim.y + (int)blockIdx.y) * tilesX + (int)blockIdx.x;
  const int swz = (bid & 7) * (nwg >> 3) + (bid >> 3);
  const int z   = swz / tilesXY;
  const int rem = swz % tilesXY;
  const int brow = (rem / tilesX) << 8;
  const int bcol = (rem % tilesX) << 8;
  A += (size_t)z * sA;
  C += (size_t)z * sC;

  // fragment-read lane constants (swizzled 16B slot is lane-constant across frags)
  const int lr = lane & 15, lg = lane >> 4, h = lr >> 1;
  const int sf = (lg + ((lr & 1) << 2)) ^ h;
  const int aoff = (wr * 64 + h) * 64 + sf * 8;      // + m*512 per frag
  const int boff = (wc * 32 + h) * 64 + sf * 8;      // + n*512 per frag

  // staging: linear LDS dest (tid*16B within piece), inverse-swizzled global source
  const int kp   = (tid & 7) ^ ((tid >> 3) & 7);
  const int srow = 2 * (tid >> 3) + (kp >> 2);
  const int scol = (kp & 3) << 3;
  const size_t gA0 = (size_t)(brow + srow) * K + scol;
  const size_t gA1 = (size_t)(brow + 128 + srow) * K + scol;
  const size_t gB0 = (size_t)(bcol + srow) * K + scol;
  const size_t gB1 = (size_t)(bcol + 128 + srow) * K + scol;
  const int sOff0 = wid * 512;
  const int sOff1 = 4096 + wid * 512;

  const int NC = K >> 5;

  f32x4 acc[8][4] = {};

#define STAGE_A(cc) do { const int _s = ((cc) & 3) * 8192; const size_t _k = (size_t)(cc) * 32; \
    gload_lds16(A + gA0 + _k, ldsA + _s + sOff0);                                               \
    gload_lds16(A + gA1 + _k, ldsA + _s + sOff1); } while (0)
#define STAGE_B(cc) do { const int _s = ((cc) & 3) * 8192; const size_t _k = (size_t)(cc) * 32; \
    gload_lds16(Bt + gB0 + _k, ldsB + _s + sOff0);                                              \
    gload_lds16(Bt + gB1 + _k, ldsB + _s + sOff1); } while (0)

  STAGE_A(0); STAGE_B(0); STAGE_A(1); STAGE_B(1); STAGE_A(2); STAGE_B(2);
  asm volatile("s_waitcnt vmcnt(8)" ::: "memory");
  __builtin_amdgcn_sched_barrier(0);
  __builtin_amdgcn_s_barrier();

  // Balanced 2-phase chunk: P0 reads 8 (aA0-3 + bb0-3), MFMA m0-3 x n0-3;
  //                         P1 reads 4 (aB0-3),          MFMA m4-7 x n0-3.
#define CHUNK(c, DOSTAGE, TAILWAIT) do {                                        \
    const int _sl = ((c) & 3) * 8192;                                           \
    const u16* _pa = ldsA + _sl + aoff;                                         \
    const u16* _pb = ldsB + _sl + boff;                                         \
    bf16x8 aA[4], aB[4], bb[4];                                                 \
    _Pragma("unroll")                                                           \
    for (int m = 0; m < 4; ++m) aA[m] = *(const bf16x8*)(_pa + m * 512);        \
    _Pragma("unroll")                                                           \
    for (int n = 0; n < 4; ++n) bb[n] = *(const bf16x8*)(_pb + n * 512);        \
    if (DOSTAGE) STAGE_A((c) + 3);                                              \
    __builtin_amdgcn_s_barrier();                                               \
    asm volatile("s_waitcnt lgkmcnt(0)" ::: "memory");                          \
    __builtin_amdgcn_sched_barrier(0);                                          \
    __builtin_amdgcn_s_setprio(1);                                              \
    _Pragma("unroll")                                                           \
    for (int m = 0; m < 4; ++m)                                                 \
      _Pragma("unroll")                                                         \
      for (int n = 0; n < 4; ++n)                                               \
        acc[m][n] = __builtin_amdgcn_mfma_f32_16x16x32_bf16(aA[m], bb[n], acc[m][n], 0, 0, 0); \
    __builtin_amdgcn_s_setprio(0);                                              \
    __builtin_amdgcn_s_barrier();                                               \
    _Pragma("unroll")                                                           \
    for (int m = 0; m < 4; ++m) aB[m] = *(const bf16x8*)(_pa + (4 + m) * 512);  \
    if (DOSTAGE) STAGE_B((c) + 3);                                              \
    __builtin_amdgcn_s_barrier();                                               \
    asm volatile("s_waitcnt lgkmcnt(0)" ::: "memory");                          \
    __builtin_amdgcn_sched_barrier(0);                                          \
    __builtin_amdgcn_s_setprio(1);                                              \
    _Pragma("unroll")                                                           \
    for (int m = 0; m < 4; ++m)                                                 \
      _Pragma("unroll")                                                         \
      for (int n = 0; n < 4; ++n)                                               \
        acc[4 + m][n] = __builtin_amdgcn_mfma_f32_16x16x32_bf16(aB[m], bb[n], acc[4 + m][n], 0, 0, 0); \
    __builtin_amdgcn_s_setprio(0);                                              \
    asm volatile("s_waitcnt " TAILWAIT ::: "memory");                           \
    __builtin_amdgcn_sched_barrier(0);                                          \
    __builtin_amdgcn_s_barrier();                                               \
  } while (0)

  for (int c = 0; c + 3 < NC; ++c) CHUNK(c, 1, "vmcnt(8)");
  CHUNK(NC - 3, 0, "vmcnt(4)");
  CHUNK(NC - 2, 0, "vmcnt(0)");
  CHUNK(NC - 1, 0, "vmcnt(0)");

#undef CHUNK
#undef STAGE_A
#undef STAGE_B

#pragma unroll
  for (int m = 0; m < 8; ++m) {
    const int r0 = brow + wr * 128 + m * 16 + lg * 4;
#pragma unroll
    for (int n = 0; n < 4; ++n) {
      const int cc = bcol + wc * 64 + n * 16 + lr;
#pragma unroll
      for (int j = 0; j < 4; ++j)
        store_out(&C[(size_t)(r0 + j) * ldC + cc], acc[m][n][j]);
    }
  }
}

// ---------------- tiled transpose: out[c][r] = bf16(in[r][c]) ----------------
__global__ void trans_kernel(const float* __restrict__ in, u16* __restrict__ out, int n) {
  __shared__ float t[32][33];
  const int bx = (int)blockIdx.x * 32, by = (int)blockIdx.y * 32;
  const int x = (int)threadIdx.x, y0 = (int)threadIdx.y;
#pragma unroll
  for (int dy = 0; dy < 32; dy += 8)
    t[y0 + dy][x] = in[(size_t)(bx + y0 + dy) * n + by + x];
  __syncthreads();
#pragma unroll
  for (int dy = 0; dy < 32; dy += 8)
    out[(size_t)(by + y0 + dy) * n + bx + x] = f2bf(t[x][y0 + dy]);
}

// Qtp[c][perm(r)] = bf16(Q[r][c]); perm(r) = ((r&1)<<11)|(r>>1)  (folds X1p interleave)
__global__ void transperm_kernel(const float* __restrict__ in, u16* __restrict__ out) {
  __shared__ float t[32][33];
  const int bx = (int)blockIdx.x * 32, by = (int)blockIdx.y * 32;
  const int x = (int)threadIdx.x, y0 = (int)threadIdx.y;
#pragma unroll
  for (int dy = 0; dy < 32; dy += 8)
    t[y0 + dy][x] = in[(size_t)(bx + y0 + dy) * 4096 + by + x];
  __syncthreads();
  const int r = bx + x;
  const int cp = ((r & 1) << 11) | (r >> 1);
#pragma unroll
  for (int dy = 0; dy < 32; dy += 8)
    out[(size_t)(by + y0 + dy) * 4096 + cp] = f2bf(t[x][y0 + dy]);
}

// rteff[i][j] = bf16(R[j][i] + D[i][j]); D[i][j] = Dsub[(i&1)*2+(j&1)][i>>1][j>>1]
__global__ void transadd_kernel(const float* __restrict__ R, const float* __restrict__ Dsub,
                                u16* __restrict__ out) {
  __shared__ float t[32][33];
  const int bx = (int)blockIdx.x * 32, by = (int)blockIdx.y * 32;
  const int x = (int)threadIdx.x, y0 = (int)threadIdx.y;
#pragma unroll
  for (int dy = 0; dy < 32; dy += 8)
    t[y0 + dy][x] = R[(size_t)(bx + y0 + dy) * 4096 + by + x];
  __syncthreads();
  const int j = bx + x;
#pragma unroll
  for (int dy = 0; dy < 32; dy += 8) {
    const int i = by + y0 + dy;
    const int s = ((i & 1) << 1) | (j & 1);
    const float d = Dsub[(size_t)s * 4194304 + ((size_t)(i >> 1) << 11) + (j >> 1)];
    out[(size_t)i * 4096 + j] = f2bf(t[x][y0 + dy] + d);
  }
}

// R1bf = bf16(R1); Asc[s][i1][k1] = bf16(R1[i1][k1] * g_s[k1]),
// g_s[k1] = lam[2k1]*R2[i2][0]*R2[j2][0] + lam[2k1+1]*R2[i2][1]*R2[j2][1], s=(i2,j2)
__global__ void scale_r1_kernel(const float* __restrict__ R1, const float* __restrict__ R2,
                                const float* __restrict__ lam,
                                u16* __restrict__ R1bf, u16* __restrict__ Asc) {
  const int idx = (int)blockIdx.x * 256 + (int)threadIdx.x;   // over 2048*512
  const int i1 = idx >> 9, k1 = (idx & 511) << 2;
  const float4 r1 = *(const float4*)(R1 + (size_t)i1 * 2048 + k1);
  const float4 l0 = *(const float4*)(lam + 2 * k1);
  const float4 l1 = *(const float4*)(lam + 2 * k1 + 4);
  const float le[4] = {l0.x, l0.z, l1.x, l1.z};
  const float lo[4] = {l0.y, l0.w, l1.y, l1.w};
  const float rv[4] = {r1.x, r1.y, r1.z, r1.w};
  ushort4 rb;
  rb.x = f2bf(r1.x); rb.y = f2bf(r1.y); rb.z = f2bf(r1.z); rb.w = f2bf(r1.w);
  *(ushort4*)(R1bf + (size_t)i1 * 2048 + k1) = rb;
#pragma unroll
  for (int s = 0; s < 4; ++s) {
    const int i2 = s >> 1, j2 = s & 1;
    const float c0 = R2[i2 * 2] * R2[j2 * 2];
    const float c1 = R2[i2 * 2 + 1] * R2[j2 * 2 + 1];
    ushort4 o;
    u16* dst = Asc + (size_t)s * 4194304 + (size_t)i1 * 2048 + k1;
    o.x = f2bf(rv[0] * (le[0] * c0 + lo[0] * c1));
    o.y = f2bf(rv[1] * (le[1] * c0 + lo[1] * c1));
    o.z = f2bf(rv[2] * (le[2] * c0 + lo[2] * c1));
    o.w = f2bf(rv[3] * (le[3] * c0 + lo[3] * c1));
    *(ushort4*)dst = o;
  }
}

// T[j2][s][k1] = bf16(in[s][2k1]*Q2[0][j2] + in[s][2k1+1]*Q2[1][j2])
__global__ void tprep_kernel(const float* __restrict__ in, const float* __restrict__ Q2,
                             u16* __restrict__ T) {
  const int idx = (int)blockIdx.x * 256 + (int)threadIdx.x;   // over 4096*512
  const int s = idx >> 9, k1 = (idx & 511) << 2;
  const float4 a = *(const float4*)(in + (size_t)s * 4096 + 2 * k1);
  const float4 b = *(const float4*)(in + (size_t)s * 4096 + 2 * k1 + 4);
  const float e[4] = {a.x, a.z, b.x, b.z};
  const float o[4] = {a.y, a.w, b.y, b.w};
  const float q00 = Q2[0], q01 = Q2[1], q10 = Q2[2], q11 = Q2[3];
  ushort4 t0, t1;
  t0.x = f2bf(e[0] * q00 + o[0] * q10); t1.x = f2bf(e[0] * q01 + o[0] * q11);
  t0.y = f2bf(e[1] * q00 + o[1] * q10); t1.y = f2bf(e[1] * q01 + o[1] * q11);
  t0.z = f2bf(e[2] * q00 + o[2] * q10); t1.z = f2bf(e[2] * q01 + o[2] * q11);
  t0.w = f2bf(e[3] * q00 + o[3] * q10); t1.w = f2bf(e[3] * q01 + o[3] * q11);
  *(ushort4*)(T + (size_t)s * 2048 + k1) = t0;
  *(ushort4*)(T + 8388608 + (size_t)s * 2048 + k1) = t1;
}

extern "C" void kernel_launch(void* const* d_in, const int* in_sizes, int n_in,
                              void* d_out, int out_size, void* d_ws, size_t ws_size,
                              hipStream_t stream) {
  const float* input = (const float*)d_in[0];
  const float* Q     = (const float*)d_in[1];
  const float* R     = (const float*)d_in[2];
  const float* Q1    = (const float*)d_in[3];
  const float* Q2    = (const float*)d_in[4];
  const float* R1    = (const float*)d_in[5];
  const float* R2    = (const float*)d_in[6];
  const float* lam   = (const float*)d_in[7];
  float* out = (float*)d_out;

  const size_t MB = 1024ull * 1024ull;
  char* ws = (char*)d_ws;
  u16* R1bf  = (u16*)(ws + 0 * MB);
  u16* Asc   = (u16*)(ws + 8 * MB);     // 4 planes of 8MB; reused as X2 later
  u16* Q1tb  = (u16*)(ws + 40 * MB);
  u16* T     = (u16*)(ws + 48 * MB);    // 2 planes of 16MB
  u16* Qtp   = (u16*)(ws + 80 * MB);
  u16* rteff = (u16*)(ws + 112 * MB);
  u16* X1p   = (u16*)(ws + 144 * MB);   // needs ws_size >= 176 MB
  u16* X2    = Asc;
  float* Dsub = (float*)d_out;          // 4 x 2048^2 f32, consumed by transadd

  {
    void (*pf)(const u16*, const u16*, float*, int, int, int, int, long long, long long) = gemm256<float>;
    void (*pb)(const u16*, const u16*, u16*, int, int, int, int, long long, long long)   = gemm256<u16>;
    (void)hipFuncSetAttribute((const void*)pf, hipFuncAttributeMaxDynamicSharedMemorySize, 131072);
    (void)hipFuncSetAttribute((const void*)pb, hipFuncAttributeMaxDynamicSharedMemorySize, 131072);
  }

  const dim3 tb(32, 8);
  // 1) Q1tb = bf16(Q1^T)
  trans_kernel<<<dim3(64, 64), tb, 0, stream>>>(Q1, Q1tb, 2048);
  // 2) Qtp = permuted bf16(Q^T)
  transperm_kernel<<<dim3(128, 128), tb, 0, stream>>>(Q, Qtp);
  // 3) R1bf + scaled copies Asc[s]
  scale_r1_kernel<<<4096, 256, 0, stream>>>(R1, R2, lam, R1bf, Asc);
  // 4) T[j2] = Q2-contraction of input
  tprep_kernel<<<8192, 256, 0, stream>>>(input, Q2, T);
  // 5) Dsub[s] = Asc[s] @ R1bf^T   (batched 4 x 2048^3)
  gemm256<float><<<dim3(8, 8, 4), 512, 131072, stream>>>(
      Asc, R1bf, Dsub, 2048, 2048, 2048, 2048, 4194304LL, 4194304LL);
  // 6) rteff = R^T + D
  transadd_kernel<<<dim3(128, 128), tb, 0, stream>>>(R, Dsub, rteff);
  // 7) X1p[:, j2*2048+j1] = T[j2] @ Q1tb^T   (batched 2 x 4096x2048x2048)
  gemm256<u16><<<dim3(8, 16, 2), 512, 131072, stream>>>(
      T, Q1tb, X1p, 4096, 2048, 2048, 4096, 8388608LL, 2048LL);
  // 8) X2 = X1p @ Qtp^T   (4096^3)
  gemm256<u16><<<dim3(16, 16, 1), 512, 131072, stream>>>(
      X1p, Qtp, X2, 4096, 4096, 4096, 4096, 0LL, 0LL);
  // 9) out = X2 @ rteff^T  (4096^3, f32)
  gemm256<float><<<dim3(16, 16, 1), 512, 131072, stream>>>(
      X2, rteff, out, 4096, 4096, 4096, 4096, 0LL, 0LL);
}

// Round 5
// 460.425 us; speedup vs baseline: 2.1137x; 1.0721x over previous
//
#include <hip/hip_runtime.h>
#include <stdint.h>

// KronQRInjectedLinear: out = ((input @ rot) @ Q) @ R_eff.
// Kron structure exploited (see r4): D via 4x2048^3 batched, rot via 2x4096x2048x2048.
// GEMM core v3: faithful m201 8-phase schedule. 256x256 tile, 8 waves (2Mx4N),
// BK=64 K-tiles, 2 LDS double-buffers, 8-KB pieces staged 2/phase staggered,
// derived counted vmcnt(4) at phases 3/7 only, B-frags register-held per K-tile,
// zero-conflict XOR swizzle (pair-packed rows), setprio, XCD swizzle.

typedef unsigned short u16;
typedef short bf16x8 __attribute__((ext_vector_type(8)));
typedef float f32x4 __attribute__((ext_vector_type(4)));

__device__ __forceinline__ u16 f2bf(float f) {
  union { float f; uint32_t u; } v; v.f = f;
  return (u16)((v.u + 0x7FFFu + ((v.u >> 16) & 1u)) >> 16);
}

__device__ __forceinline__ void store_out(float* p, float v) { *p = v; }
__device__ __forceinline__ void store_out(u16* p, float v) { *p = f2bf(v); }

__device__ __forceinline__ void gload_lds16(const u16* g, u16* l) {
  __builtin_amdgcn_global_load_lds(
      (__attribute__((address_space(1))) void*)(uintptr_t)g,
      (__attribute__((address_space(3))) void*)l, 16, 0, 0);
}

#define MFMA16(a, b, c) __builtin_amdgcn_mfma_f32_16x16x32_bf16((a), (b), (c), 0, 0, 0)

// ---------------- GEMM: C[M,N] = A[M,K] @ Bt[N,K]^T (batched on z) ----------------
// LDS piece (8 KB) = 128 rows x 32 k, pair-packed: elem (rp,kk) ->
//   (rp>>1)*64 + ((((kk>>3)+4*(rp&1)) ^ ((rp>>1)&7))*8) + (kk&7)
// A K-tile buffer = 4 pieces [rh][ks]; 2 buffers each for A and B (128 KB total).
template <typename OutT>
__global__ __launch_bounds__(512, 2) void gemm256(
    const u16* __restrict__ A, const u16* __restrict__ Bt, OutT* __restrict__ C,
    int M, int N, int K, int ldC, long long sA, long long sC) {
  extern __shared__ __align__(16) u16 smem[];
  u16* ldsA = smem;           // 2 bufs x 16384 elems (64 KB)
  u16* ldsB = smem + 32768;

  const int tid  = (int)threadIdx.x;
  const int lane = tid & 63;
  const int wid  = tid >> 6;
  const int wr   = wid >> 2;       // 0..1 : M half (128 rows)
  const int wc   = wid & 3;        // 0..3 : N quarter (64 cols)

  // XCD-aware bijective swizzle (nwg % 8 == 0 for all our grids)
  const int tilesX = (int)gridDim.x;
  const int tilesXY = tilesX * (int)gridDim.y;
  const int nwg = tilesXY * (int)gridDim.z;
  const int bid = ((int)blockIdx.z * (int)gridDim.y + (int)blockIdx.y) * tilesX + (int)blockIdx.x;
  const int swz = (bid & 7) * (nwg >> 3) + (bid >> 3);
  const int z   = swz / tilesXY;
  const int rem = swz % tilesXY;
  const int brow = (rem / tilesX) << 8;
  const int bcol = (rem % tilesX) << 8;
  A += (size_t)z * sA;
  C += (size_t)z * sC;

  // fragment-read lane constants (swizzled 16B slot is lane-constant)
  const int lr = lane & 15, lg = lane >> 4, h = lr >> 1;
  const int sf = (lg + ((lr & 1) << 2)) ^ h;
  const int abase = wr * 8192 + h * 64 + sf * 8;                    // + frag*512 + ks*4096 + buf*16384
  const int bbase = (wc >> 1) * 8192 + ((wc & 1) * 32 + h) * 64 + sf * 8;

  // staging: linear LDS dest (tid*16B within 8KB piece), inverse-swizzled source
  const int kp   = (tid & 7) ^ ((tid >> 3) & 7);
  const int srow = 2 * (tid >> 3) + (kp >> 2);
  const int scol = (kp & 3) << 3;
  const size_t gA0 = (size_t)(brow + srow) * K + scol;
  const size_t gB0 = (size_t)(bcol + srow) * K + scol;
  const size_t rstep = (size_t)K << 7;     // 128 rows
  const int sdst = wid * 512;

  const int NC = K >> 6;                   // 64-wide K-tiles (even, >= 4)
  const int NI = NC >> 1;

  f32x4 acc[8][4] = {};
  bf16x8 af[4][2], bf[4][2];

#define STG_A(t, rh, ks) gload_lds16(A + gA0 + (rh) * rstep + (size_t)(t) * 64 + (ks) * 32, \
    ldsA + ((t) & 1) * 16384 + (rh) * 8192 + (ks) * 4096 + sdst)
#define STG_B(t, rh, ks) gload_lds16(Bt + gB0 + (rh) * rstep + (size_t)(t) * 64 + (ks) * 32, \
    ldsB + ((t) & 1) * 16384 + (rh) * 8192 + (ks) * 4096 + sdst)
#define VM4 asm volatile("s_waitcnt vmcnt(4)" ::: "memory")
#define VM0 asm volatile("s_waitcnt vmcnt(0)" ::: "memory")

  // Phase: optional ds_reads + 2 staged pieces -> barrier -> lgkm(0) -> 16 MFMA -> tail -> barrier
#define PH(BUF, MH, RDA, RDB01, RDB23, N0, N1, S0, S1, TAIL) do {               \
    const u16* _pa = ldsA + (BUF) * 16384 + abase;                              \
    const u16* _pb = ldsB + (BUF) * 16384 + bbase;                              \
    if (RDA) {                                                                  \
      _Pragma("unroll")                                                         \
      for (int m = 0; m < 4; ++m) {                                             \
        af[m][0] = *(const bf16x8*)(_pa + ((MH) * 4 + m) * 512);                \
        af[m][1] = *(const bf16x8*)(_pa + ((MH) * 4 + m) * 512 + 4096);         \
      }                                                                         \
    }                                                                           \
    if (RDB01) {                                                                \
      bf[0][0] = *(const bf16x8*)(_pb);        bf[0][1] = *(const bf16x8*)(_pb + 4096);       \
      bf[1][0] = *(const bf16x8*)(_pb + 512);  bf[1][1] = *(const bf16x8*)(_pb + 512 + 4096); \
    }                                                                           \
    if (RDB23) {                                                                \
      bf[2][0] = *(const bf16x8*)(_pb + 1024); bf[2][1] = *(const bf16x8*)(_pb + 1024 + 4096); \
      bf[3][0] = *(const bf16x8*)(_pb + 1536); bf[3][1] = *(const bf16x8*)(_pb + 1536 + 4096); \
    }                                                                           \
    S0; S1;                                                                     \
    __builtin_amdgcn_s_barrier();                                               \
    asm volatile("s_waitcnt lgkmcnt(0)" ::: "memory");                          \
    __builtin_amdgcn_sched_barrier(0);                                          \
    __builtin_amdgcn_s_setprio(1);                                              \
    _Pragma("unroll")                                                           \
    for (int m = 0; m < 4; ++m) {                                               \
      acc[(MH) * 4 + m][N0] = MFMA16(af[m][0], bf[N0][0], acc[(MH) * 4 + m][N0]); \
      acc[(MH) * 4 + m][N0] = MFMA16(af[m][1], bf[N0][1], acc[(MH) * 4 + m][N0]); \
      acc[(MH) * 4 + m][N1] = MFMA16(af[m][0], bf[N1][0], acc[(MH) * 4 + m][N1]); \
      acc[(MH) * 4 + m][N1] = MFMA16(af[m][1], bf[N1][1], acc[(MH) * 4 + m][N1]); \
    }                                                                           \
    __builtin_amdgcn_s_setprio(0);                                              \
    TAIL;                                                                       \
    __builtin_amdgcn_sched_barrier(0);                                          \
    __builtin_amdgcn_s_barrier();                                               \
  } while (0)

  // Prologue: A(0), B(0), B(1); wait A(0)+B(0) (leave B(1)'s 4 in flight).
  STG_A(0, 0, 0); STG_A(0, 0, 1); STG_A(0, 1, 0); STG_A(0, 1, 1);
  STG_B(0, 0, 0); STG_B(0, 0, 1); STG_B(0, 1, 0); STG_B(0, 1, 1);
  STG_B(1, 0, 0); STG_B(1, 0, 1); STG_B(1, 1, 0); STG_B(1, 1, 1);
  VM4;
  __builtin_amdgcn_sched_barrier(0);
  __builtin_amdgcn_s_barrier();

  // Steady state. Iter i: compute tiles 2i (buf0), 2i+1 (buf1);
  // stage A(2i+1) @p0-1, B(2i+2) @p2-3, A(2i+2) @p4-5, B(2i+3) @p6-7.
  for (int i = 0; i < NI - 1; ++i) {
    const int tn = 2 * i;
    PH(0, 0, 1, 1, 0, 0, 1, STG_A(tn + 1, 0, 0), STG_A(tn + 1, 0, 1), (void)0);
    PH(0, 0, 0, 0, 1, 2, 3, STG_A(tn + 1, 1, 0), STG_A(tn + 1, 1, 1), (void)0);
    PH(0, 1, 1, 0, 0, 0, 1, STG_B(tn + 2, 0, 0), STG_B(tn + 2, 0, 1), (void)0);
    PH(0, 1, 0, 0, 0, 2, 3, STG_B(tn + 2, 1, 0), STG_B(tn + 2, 1, 1), VM4);
    PH(1, 0, 1, 1, 0, 0, 1, STG_A(tn + 2, 0, 0), STG_A(tn + 2, 0, 1), (void)0);
    PH(1, 0, 0, 0, 1, 2, 3, STG_A(tn + 2, 1, 0), STG_A(tn + 2, 1, 1), (void)0);
    PH(1, 1, 1, 0, 0, 0, 1, STG_B(tn + 3, 0, 0), STG_B(tn + 3, 0, 1), (void)0);
    PH(1, 1, 0, 0, 0, 2, 3, STG_B(tn + 3, 1, 0), STG_B(tn + 3, 1, 1), VM4);
  }
  // Last iter: only A(NC-1) still needed; drain fully at p3.
  {
    PH(0, 0, 1, 1, 0, 0, 1, STG_A(NC - 1, 0, 0), STG_A(NC - 1, 0, 1), (void)0);
    PH(0, 0, 0, 0, 1, 2, 3, STG_A(NC - 1, 1, 0), STG_A(NC - 1, 1, 1), (void)0);
    PH(0, 1, 1, 0, 0, 0, 1, (void)0, (void)0, (void)0);
    PH(0, 1, 0, 0, 0, 2, 3, (void)0, (void)0, VM0);
    PH(1, 0, 1, 1, 0, 0, 1, (void)0, (void)0, (void)0);
    PH(1, 0, 0, 0, 1, 2, 3, (void)0, (void)0, (void)0);
    PH(1, 1, 1, 0, 0, 0, 1, (void)0, (void)0, (void)0);
    PH(1, 1, 0, 0, 0, 2, 3, (void)0, (void)0, (void)0);
  }

#undef PH
#undef STG_A
#undef STG_B
#undef VM4
#undef VM0

  // C/D layout per 16x16 frag: col = lane&15, row = (lane>>4)*4 + j
#pragma unroll
  for (int m = 0; m < 8; ++m) {
    const int r0 = brow + wr * 128 + m * 16 + lg * 4;
#pragma unroll
    for (int n = 0; n < 4; ++n) {
      const int cc = bcol + wc * 64 + n * 16 + lr;
#pragma unroll
      for (int j = 0; j < 4; ++j)
        store_out(&C[(size_t)(r0 + j) * ldC + cc], acc[m][n][j]);
    }
  }
}

// ---------------- tiled transpose: out[c][r] = bf16(in[r][c]) ----------------
__global__ void trans_kernel(const float* __restrict__ in, u16* __restrict__ out, int n) {
  __shared__ float t[32][33];
  const int bx = (int)blockIdx.x * 32, by = (int)blockIdx.y * 32;
  const int x = (int)threadIdx.x, y0 = (int)threadIdx.y;
#pragma unroll
  for (int dy = 0; dy < 32; dy += 8)
    t[y0 + dy][x] = in[(size_t)(bx + y0 + dy) * n + by + x];
  __syncthreads();
#pragma unroll
  for (int dy = 0; dy < 32; dy += 8)
    out[(size_t)(by + y0 + dy) * n + bx + x] = f2bf(t[x][y0 + dy]);
}

// Qtp[c][perm(r)] = bf16(Q[r][c]); perm(r) = ((r&1)<<11)|(r>>1)
__global__ void transperm_kernel(const float* __restrict__ in, u16* __restrict__ out) {
  __shared__ float t[32][33];
  const int bx = (int)blockIdx.x * 32, by = (int)blockIdx.y * 32;
  const int x = (int)threadIdx.x, y0 = (int)threadIdx.y;
#pragma unroll
  for (int dy = 0; dy < 32; dy += 8)
    t[y0 + dy][x] = in[(size_t)(bx + y0 + dy) * 4096 + by + x];
  __syncthreads();
  const int r = bx + x;
  const int cp = ((r & 1) << 11) | (r >> 1);
#pragma unroll
  for (int dy = 0; dy < 32; dy += 8)
    out[(size_t)(by + y0 + dy) * 4096 + cp] = f2bf(t[x][y0 + dy]);
}

// rteff[i][j] = bf16(R[j][i] + D[i][j]); D[i][j] = Dsub[(i&1)*2+(j&1)][i>>1][j>>1]
__global__ void transadd_kernel(const float* __restrict__ R, const float* __restrict__ Dsub,
                                u16* __restrict__ out) {
  __shared__ float t[32][33];
  const int bx = (int)blockIdx.x * 32, by = (int)blockIdx.y * 32;
  const int x = (int)threadIdx.x, y0 = (int)threadIdx.y;
#pragma unroll
  for (int dy = 0; dy < 32; dy += 8)
    t[y0 + dy][x] = R[(size_t)(bx + y0 + dy) * 4096 + by + x];
  __syncthreads();
  const int j = bx + x;
#pragma unroll
  for (int dy = 0; dy < 32; dy += 8) {
    const int i = by + y0 + dy;
    const int s = ((i & 1) << 1) | (j & 1);
    const float d = Dsub[(size_t)s * 4194304 + ((size_t)(i >> 1) << 11) + (j >> 1)];
    out[(size_t)i * 4096 + j] = f2bf(t[x][y0 + dy] + d);
  }
}

// R1bf = bf16(R1); Asc[s][i1][k1] = bf16(R1[i1][k1] * g_s[k1])
__global__ void scale_r1_kernel(const float* __restrict__ R1, const float* __restrict__ R2,
                                const float* __restrict__ lam,
                                u16* __restrict__ R1bf, u16* __restrict__ Asc) {
  const int idx = (int)blockIdx.x * 256 + (int)threadIdx.x;   // over 2048*512
  const int i1 = idx >> 9, k1 = (idx & 511) << 2;
  const float4 r1 = *(const float4*)(R1 + (size_t)i1 * 2048 + k1);
  const float4 l0 = *(const float4*)(lam + 2 * k1);
  const float4 l1 = *(const float4*)(lam + 2 * k1 + 4);
  const float le[4] = {l0.x, l0.z, l1.x, l1.z};
  const float lo[4] = {l0.y, l0.w, l1.y, l1.w};
  const float rv[4] = {r1.x, r1.y, r1.z, r1.w};
  ushort4 rb;
  rb.x = f2bf(r1.x); rb.y = f2bf(r1.y); rb.z = f2bf(r1.z); rb.w = f2bf(r1.w);
  *(ushort4*)(R1bf + (size_t)i1 * 2048 + k1) = rb;
#pragma unroll
  for (int s = 0; s < 4; ++s) {
    const int i2 = s >> 1, j2 = s & 1;
    const float c0 = R2[i2 * 2] * R2[j2 * 2];
    const float c1 = R2[i2 * 2 + 1] * R2[j2 * 2 + 1];
    ushort4 o;
    u16* dst = Asc + (size_t)s * 4194304 + (size_t)i1 * 2048 + k1;
    o.x = f2bf(rv[0] * (le[0] * c0 + lo[0] * c1));
    o.y = f2bf(rv[1] * (le[1] * c0 + lo[1] * c1));
    o.z = f2bf(rv[2] * (le[2] * c0 + lo[2] * c1));
    o.w = f2bf(rv[3] * (le[3] * c0 + lo[3] * c1));
    *(ushort4*)dst = o;
  }
}

// T[j2][s][k1] = bf16(in[s][2k1]*Q2[0][j2] + in[s][2k1+1]*Q2[1][j2])
__global__ void tprep_kernel(const float* __restrict__ in, const float* __restrict__ Q2,
                             u16* __restrict__ T) {
  const int idx = (int)blockIdx.x * 256 + (int)threadIdx.x;   // over 4096*512
  const int s = idx >> 9, k1 = (idx & 511) << 2;
  const float4 a = *(const float4*)(in + (size_t)s * 4096 + 2 * k1);
  const float4 b = *(const float4*)(in + (size_t)s * 4096 + 2 * k1 + 4);
  const float e[4] = {a.x, a.z, b.x, b.z};
  const float o[4] = {a.y, a.w, b.y, b.w};
  const float q00 = Q2[0], q01 = Q2[1], q10 = Q2[2], q11 = Q2[3];
  ushort4 t0, t1;
  t0.x = f2bf(e[0] * q00 + o[0] * q10); t1.x = f2bf(e[0] * q01 + o[0] * q11);
  t0.y = f2bf(e[1] * q00 + o[1] * q10); t1.y = f2bf(e[1] * q01 + o[1] * q11);
  t0.z = f2bf(e[2] * q00 + o[2] * q10); t1.z = f2bf(e[2] * q01 + o[2] * q11);
  t0.w = f2bf(e[3] * q00 + o[3] * q10); t1.w = f2bf(e[3] * q01 + o[3] * q11);
  *(ushort4*)(T + (size_t)s * 2048 + k1) = t0;
  *(ushort4*)(T + 8388608 + (size_t)s * 2048 + k1) = t1;
}

extern "C" void kernel_launch(void* const* d_in, const int* in_sizes, int n_in,
                              void* d_out, int out_size, void* d_ws, size_t ws_size,
                              hipStream_t stream) {
  const float* input = (const float*)d_in[0];
  const float* Q     = (const float*)d_in[1];
  const float* R     = (const float*)d_in[2];
  const float* Q1    = (const float*)d_in[3];
  const float* Q2    = (const float*)d_in[4];
  const float* R1    = (const float*)d_in[5];
  const float* R2    = (const float*)d_in[6];
  const float* lam   = (const float*)d_in[7];
  float* out = (float*)d_out;

  const size_t MB = 1024ull * 1024ull;
  char* ws = (char*)d_ws;
  u16* R1bf  = (u16*)(ws + 0 * MB);
  u16* Asc   = (u16*)(ws + 8 * MB);     // 4 planes of 8MB; reused as X2 later
  u16* Q1tb  = (u16*)(ws + 40 * MB);
  u16* T     = (u16*)(ws + 48 * MB);    // 2 planes of 16MB
  u16* Qtp   = (u16*)(ws + 80 * MB);
  u16* rteff = (u16*)(ws + 112 * MB);
  u16* X1p   = (u16*)(ws + 144 * MB);   // needs ws_size >= 176 MB
  u16* X2    = Asc;
  float* Dsub = (float*)d_out;          // 4 x 2048^2 f32, consumed by transadd

  {
    void (*pf)(const u16*, const u16*, float*, int, int, int, int, long long, long long) = gemm256<float>;
    void (*pb)(const u16*, const u16*, u16*, int, int, int, int, long long, long long)   = gemm256<u16>;
    (void)hipFuncSetAttribute((const void*)pf, hipFuncAttributeMaxDynamicSharedMemorySize, 131072);
    (void)hipFuncSetAttribute((const void*)pb, hipFuncAttributeMaxDynamicSharedMemorySize, 131072);
  }

  const dim3 tb(32, 8);
  // 1) Q1tb = bf16(Q1^T)
  trans_kernel<<<dim3(64, 64), tb, 0, stream>>>(Q1, Q1tb, 2048);
  // 2) Qtp = permuted bf16(Q^T)
  transperm_kernel<<<dim3(128, 128), tb, 0, stream>>>(Q, Qtp);
  // 3) R1bf + scaled copies Asc[s]
  scale_r1_kernel<<<4096, 256, 0, stream>>>(R1, R2, lam, R1bf, Asc);
  // 4) T[j2] = Q2-contraction of input
  tprep_kernel<<<8192, 256, 0, stream>>>(input, Q2, T);
  // 5) Dsub[s] = Asc[s] @ R1bf^T   (batched 4 x 2048^3)
  gemm256<float><<<dim3(8, 8, 4), 512, 131072, stream>>>(
      Asc, R1bf, Dsub, 2048, 2048, 2048, 2048, 4194304LL, 4194304LL);
  // 6) rteff = R^T + D
  transadd_kernel<<<dim3(128, 128), tb, 0, stream>>>(R, Dsub, rteff);
  // 7) X1p[:, j2*2048+j1] = T[j2] @ Q1tb^T   (batched 2 x 4096x2048x2048)
  gemm256<u16><<<dim3(8, 16, 2), 512, 131072, stream>>>(
      T, Q1tb, X1p, 4096, 2048, 2048, 4096, 8388608LL, 2048LL);
  // 8) X2 = X1p @ Qtp^T   (4096^3)
  gemm256<u16><<<dim3(16, 16, 1), 512, 131072, stream>>>(
      X1p, Qtp, X2, 4096, 4096, 4096, 4096, 0LL, 0LL);
  // 9) out = X2 @ rteff^T  (4096^3, f32)
  gemm256<float><<<dim3(16, 16, 1), 512, 131072, stream>>>(
      X2, rteff, out, 4096, 4096, 4096, 4096, 0LL, 0LL);
}